// Round 14
// baseline (122.392 us; speedup 1.0000x reference)
//
#include <hip/hip_runtime.h>
#include <hip/hip_bf16.h>
#include <math.h>

// B=2, C=128, T=5 (Tc=4 ctx), H=W=48, heads=64, PATCH=7 (pad 3), K=196.
#define BATCH 2
#define CCH 128
#define TT 5
#define TC 4
#define HH 48
#define WW 48
#define HWPIX 2304
#define NHEAD 64
#define PAD 3
#define XSTRIDE (TT*HWPIX)      // per-channel stride in x
#define ROWP 54                 // 48 + 2*3 padded rows
#define COLP 56                 // 48 + 2*3 padded cols (+2 align slack)
#define PLANE (ROWP*COLP*NHEAD) // elements per (b,t) plane

typedef unsigned short bf16_t;

static __device__ __forceinline__ bf16_t f2bf(float f) {
    unsigned u = __float_as_uint(f);
    u += 0x7FFFu + ((u >> 16) & 1u);          // round-to-nearest-even
    return (bf16_t)(u >> 16);
}
static __device__ __forceinline__ float bf_lo(unsigned u) {
    return __uint_as_float(u << 16);
}
static __device__ __forceinline__ float bf_hi(unsigned u) {
    return __uint_as_float(u & 0xFFFF0000u);
}

#if defined(__has_builtin)
#if __has_builtin(__builtin_amdgcn_fdot2_f32_bf16) && __has_builtin(__builtin_amdgcn_perm)
#define HAVE_DOT2 1
#endif
#endif

#ifdef HAVE_DOT2
typedef __bf16 bf16x2_t __attribute__((ext_vector_type(2)));
static __device__ __forceinline__ float dot2bf(unsigned g2, unsigned a2, float c) {
    return __builtin_amdgcn_fdot2_f32_bf16(
        __builtin_bit_cast(bf16x2_t, g2), __builtin_bit_cast(bf16x2_t, a2), c, false);
}
static __device__ __forceinline__ unsigned perm_lo(unsigned a, unsigned b) {
    return __builtin_amdgcn_perm(a, b, 0x05040100u);
}
static __device__ __forceinline__ unsigned perm_hi(unsigned a, unsigned b) {
    return __builtin_amdgcn_perm(a, b, 0x07060302u);
}
#else
static __device__ __forceinline__ float dot2bf(unsigned g2, unsigned a2, float c) {
    return c + bf_lo(g2) * bf_lo(a2) + bf_hi(g2) * bf_hi(a2);
}
#endif

// ---------------------------------------------------------------------------
// K0: weight reshapes, 20 blocks (R12 version).
// wt/wp/wg_pk: [16 chunk][64 h] uint4 = 4 bf16-pairs (8 consecutive c).
// wo_t: [64h][128c] fp32 transpose of w_out.
// ---------------------------------------------------------------------------
__global__ __launch_bounds__(256) void wtrans_kernel(
    const float* __restrict__ w_theta,
    const float* __restrict__ w_phi,
    const float* __restrict__ w_g,
    const float* __restrict__ w_out,
    uint4* __restrict__ wt_pk,
    uint4* __restrict__ wp_pk,
    uint4* __restrict__ wg_pk,
    float* __restrict__ wo_t)
{
    const int blk = blockIdx.x;          // 0..19
    const int tid = threadIdx.x;
    if (blk < 12) {
        const float* srcs[3] = {w_theta, w_phi, w_g};
        uint4*       dsts[3] = {wt_pk, wp_pk, wg_pk};
        const int a   = blk >> 2;
        const int idx = ((blk & 3) << 8) | tid;   // 0..1023
        const int h   = idx >> 4;                 // 0..63
        const int ck  = idx & 15;                 // chunk 0..15
        const float* s = srcs[a] + h * CCH + ck * 8;
        uint4 o;
        o.x = (unsigned)f2bf(s[0]) | ((unsigned)f2bf(s[1]) << 16);
        o.y = (unsigned)f2bf(s[2]) | ((unsigned)f2bf(s[3]) << 16);
        o.z = (unsigned)f2bf(s[4]) | ((unsigned)f2bf(s[5]) << 16);
        o.w = (unsigned)f2bf(s[6]) | ((unsigned)f2bf(s[7]) << 16);
        dsts[a][(ck << 6) | h] = o;
    } else {
        const int idx = ((blk - 12) << 8) | tid;  // 0..2047
        const int c   = idx >> 4;
        const int hq  = idx & 15;
        const float4 v = *(const float4*)(w_out + c * NHEAD + hq * 4);
        wo_t[(hq * 4 + 0) * CCH + c] = v.x;
        wo_t[(hq * 4 + 1) * CCH + c] = v.y;
        wo_t[(hq * 4 + 2) * CCH + c] = v.z;
        wo_t[(hq * 4 + 3) * CCH + c] = v.w;
    }
}

// ---------------------------------------------------------------------------
// K1: projections, fully LDS-resident inner loop, bf16 dot2 math (R12).
// ---------------------------------------------------------------------------
__global__ __launch_bounds__(256) void proj_kernel(
    const float* __restrict__ x,
    const uint4* __restrict__ wt_pk,
    const uint4* __restrict__ wp_pk,
    const uint4* __restrict__ wg_pk,
    bf16_t* __restrict__ q_b,
    bf16_t* __restrict__ phi_b,
    bf16_t* __restrict__ g_b)
{
    __shared__ unsigned xs[16 * 68];    // 4.25 KB (bf16 c-pairs, pitch 68)
    __shared__ uint4 wlA[1024];         // 16 KB
    __shared__ uint4 wlB[1024];         // 16 KB

    const int bt   = blockIdx.y;        // 0..9
    const int b    = bt / TT;
    const int t    = bt % TT;
    const int tid  = threadIdx.x;
    const int lane = tid & 63;
    const int wv   = tid >> 6;
    const int p0   = blockIdx.x * 16;

    // ---- stage weights into LDS (coalesced uint4) ----
    {
        const uint4* srcA = (t == 0) ? wt_pk : wp_pk;
#pragma unroll
        for (int i = 0; i < 4; ++i) wlA[i * 256 + tid] = srcA[i * 256 + tid];
        if (t != 0) {
#pragma unroll
            for (int i = 0; i < 4; ++i) wlB[i * 256 + tid] = wg_pk[i * 256 + tid];
        }
    }

    // ---- stage x tile as bf16 pairs (lanes over px: coalesced) ----
    {
        const float* xsrc = x + ((size_t)(b * CCH) * TT + t) * HWPIX + p0;
#pragma unroll
        for (int i = 0; i < 4; ++i) {
            const int idx = i * 256 + tid;  // 0..1023
            const int cp  = idx >> 4;       // c-pair 0..63
            const int px  = idx & 15;
            const float a0 = xsrc[(size_t)(2 * cp)     * XSTRIDE + px];
            const float a1 = xsrc[(size_t)(2 * cp + 1) * XSTRIDE + px];
            xs[px * 68 + cp] = (unsigned)f2bf(a0) | ((unsigned)f2bf(a1) << 16);
        }
    }
    __syncthreads();

    const int pxb = wv * 4;

    if (t == 0) {
        float acc[4] = {0.f, 0.f, 0.f, 0.f};
#pragma unroll 4
        for (int ck = 0; ck < 16; ++ck) {
            const uint4 wa = wlA[(ck << 6) | lane];
#pragma unroll
            for (int p = 0; p < 4; ++p) {
                const uint4 xv = *(const uint4*)&xs[(pxb + p) * 68 + (ck << 2)];
                acc[p] = dot2bf(wa.x, xv.x, acc[p]);
                acc[p] = dot2bf(wa.y, xv.y, acc[p]);
                acc[p] = dot2bf(wa.z, xv.z, acc[p]);
                acc[p] = dot2bf(wa.w, xv.w, acc[p]);
            }
        }
#pragma unroll
        for (int p = 0; p < 4; ++p)
            q_b[((size_t)b * HWPIX + p0 + pxb + p) * NHEAD + lane] = f2bf(acc[p]);
    } else {
        float accp[4] = {0.f, 0.f, 0.f, 0.f};
        float accg[4] = {0.f, 0.f, 0.f, 0.f};
#pragma unroll 4
        for (int ck = 0; ck < 16; ++ck) {
            const uint4 wa = wlA[(ck << 6) | lane];
            const uint4 wb = wlB[(ck << 6) | lane];
#pragma unroll
            for (int p = 0; p < 4; ++p) {
                const uint4 xv = *(const uint4*)&xs[(pxb + p) * 68 + (ck << 2)];
                accp[p] = dot2bf(wa.x, xv.x, accp[p]);
                accp[p] = dot2bf(wa.y, xv.y, accp[p]);
                accp[p] = dot2bf(wa.z, xv.z, accp[p]);
                accp[p] = dot2bf(wa.w, xv.w, accp[p]);
                accg[p] = dot2bf(wb.x, xv.x, accg[p]);
                accg[p] = dot2bf(wb.y, xv.y, accg[p]);
                accg[p] = dot2bf(wb.z, xv.z, accg[p]);
                accg[p] = dot2bf(wb.w, xv.w, accg[p]);
            }
        }
        const size_t base = (size_t)(b * TC + (t - 1)) * PLANE;
#pragma unroll
        for (int p = 0; p < 4; ++p) {
            const int pix = p0 + pxb + p;
            const int X = pix / WW;
            const int Y = pix % WW;
            const int rs = (X == 0) ? 0 : (X + PAD);
            const int rn = (X == 0 || X == HH - 1) ? (PAD + 1) : 1;
            const int cs = (Y == 0) ? 0 : (Y + PAD);
            const int cn = (Y == 0 || Y == WW - 1) ? (PAD + 1) : 1;
            const bf16_t vp = f2bf(accp[p]);
            const bf16_t vg = f2bf(accg[p]);
            for (int r = 0; r < rn; ++r)
                for (int c = 0; c < cn; ++c) {
                    const size_t pos = base + ((size_t)(rs + r) * COLP + (cs + c)) * NHEAD + lane;
                    phi_b[pos] = vp;
                    g_b[pos]   = vg;
                }
        }
    }
}

// ---------------------------------------------------------------------------
// K2: per-t attention partial. Single 19.7 KB LDS window (R12 occupancy),
// but BOTH windows' global loads are issued up front into registers: g's
// fetch latency hides behind phi compute. 3 barriers, zero exposed 2nd trip.
// ---------------------------------------------------------------------------
__global__ __launch_bounds__(256) void attn_kernel(
    const bf16_t* __restrict__ q_b,
    const bf16_t* __restrict__ phi_b,
    const bf16_t* __restrict__ g_b,
    float* __restrict__ part_ml,
    bf16_t* __restrict__ part_y)
{
    __shared__ bf16_t win[154 * NHEAD];     // 19.7 KB raw bf16, swizzled
    __shared__ float ls[16][52];            // 49 exp-weights per px
    __shared__ unsigned ls2[16][26];        // packed bf16 weight pairs
    __shared__ unsigned prow[26];           // (row0 | row1<<16) per pair

    const int tid = threadIdx.x;
    const int px  = tid >> 4;
    const int sub = tid & 15;
    const int bi  = blockIdx.x;
    const int btc = bi & 7;                 // b*4 + t
    const int b   = btc >> 2;
    const int t   = btc & 3;
    const int rest = bi >> 3;               // 0..143
    const int Y0  = (rest % 3) * 16;
    const int X   = rest / 3;               // 0..47
    const int gpix = X * WW + Y0 + px;

    // ---- issue ALL global loads up front: phi + g windows (regs), q ----
    uint4 up[5], ug[5];
    int   slot[5];
    {
        const bf16_t* srcP = phi_b + (size_t)(b * TC + t) * PLANE;
        const bf16_t* srcG = g_b   + (size_t)(b * TC + t) * PLANE;
#pragma unroll
        for (int i = 0; i < 5; ++i) {
            const int idx = tid + i * 256;
            if (idx < 1232) {
                const int row = idx >> 3;
                const int ch  = idx & 7;
                const int r_  = row / 22;
                const int c_  = row - r_ * 22;
                const size_t off = ((size_t)((X + r_) * COLP) + Y0 + c_) * NHEAD + ch * 8;
                up[i] = *(const uint4*)(srcP + off);
                ug[i] = *(const uint4*)(srcG + off);
                slot[i] = row * 64 + (((ch + row) & 7) << 3);
            } else {
                slot[i] = -1;
            }
        }
    }
    uint4 qu[8];
    {
        const uint4* qs = (const uint4*)(q_b + ((size_t)b * HWPIX + gpix) * NHEAD);
#pragma unroll
        for (int ch = 0; ch < 8; ++ch) qu[ch] = qs[ch];
    }

    if (tid < 25) {
        const int k0 = 2 * tid;
        const int k1 = (k0 + 1 < 49) ? k0 + 1 : 48;
        const unsigned r0 = (k0 / 7) * 22 + (k0 % 7);
        const unsigned r1 = (k1 / 7) * 22 + (k1 % 7);
        prow[tid] = r0 | (r1 << 16);
    }

    // ---- write phi window to LDS ----
#pragma unroll
    for (int i = 0; i < 5; ++i)
        if (slot[i] >= 0) *(uint4*)&win[slot[i]] = up[i];
    __syncthreads();

    // ---- 49-key logits ----
    float v[4];
#pragma unroll
    for (int r = 0; r < 4; ++r) {
        const int k = sub + 16 * r;
        float d = -INFINITY;
        if (k < 49) {
            const int i = k / 7;
            const int j = k - i * 7;
            const int row = i * 22 + j + px;
            const bf16_t* base = &win[row * 64];
            float s = 0.f;
#pragma unroll
            for (int ch = 0; ch < 8; ++ch) {
                const uint4 u = *(const uint4*)&base[((ch + row) & 7) << 3];
                s = dot2bf(u.x, qu[ch].x, s);
                s = dot2bf(u.y, qu[ch].y, s);
                s = dot2bf(u.z, qu[ch].z, s);
                s = dot2bf(u.w, qu[ch].w, s);
            }
            d = s * 8.0f;    // * sqrt(64)
        }
        v[r] = d;
    }
    float m = fmaxf(fmaxf(v[0], v[1]), fmaxf(v[2], v[3]));
#pragma unroll
    for (int d = 1; d < 16; d <<= 1) m = fmaxf(m, __shfl_xor(m, d));
    float lsum = 0.f;
#pragma unroll
    for (int r = 0; r < 4; ++r) {
        const int k = sub + 16 * r;
        if (k < 49) {
            const float e = __expf(v[r] - m);
            ls[px][k] = e;
            lsum += e;
        }
    }
#pragma unroll
    for (int d = 1; d < 16; d <<= 1) lsum += __shfl_xor(lsum, d);
    if (sub == 0) {
        *(float2*)&part_ml[((size_t)(b * TC + t) * HWPIX + gpix) * 2] = make_float2(m, lsum);
    }

    // pack weight pairs (same-wave ls traffic: no barrier)
#pragma unroll
    for (int mq = 0; mq < 2; ++mq) {
        const int mm = sub + 16 * mq;
        if (mm < 25) {
            const float a0 = ls[px][2 * mm];
            const float a1 = (2 * mm + 1 < 49) ? ls[px][2 * mm + 1] : 0.f;
            ls2[px][mm] = (unsigned)f2bf(a0) | ((unsigned)f2bf(a1) << 16);
        }
    }
    __syncthreads();     // all phi reads done

    // ---- write g window (already in registers — no global wait) ----
#pragma unroll
    for (int i = 0; i < 5; ++i)
        if (slot[i] >= 0) *(uint4*)&win[slot[i]] = ug[i];
    __syncthreads();

    // ---- unnormalized y partial: thread = (px, oct, par) over key-pairs ----
    {
        const int oct = sub >> 1;
        const int par = sub & 1;
        float acc[8];
#pragma unroll
        for (int e = 0; e < 8; ++e) acc[e] = 0.f;
#ifdef HAVE_DOT2
#pragma unroll
        for (int mm = 0; mm < 13; ++mm) {
            const int pm = 2 * mm + par;
            if (pm < 25) {
                const unsigned pr = prow[pm];
                const int row0 = (int)(pr & 0xFFFFu) + px;
                const int row1 = (int)(pr >> 16) + px;
                const unsigned a2 = ls2[px][pm];
                const uint4 u0 = *(const uint4*)&win[row0 * 64 + (((oct + row0) & 7) << 3)];
                const uint4 u1 = *(const uint4*)&win[row1 * 64 + (((oct + row1) & 7) << 3)];
                acc[0] = dot2bf(perm_lo(u1.x, u0.x), a2, acc[0]);
                acc[1] = dot2bf(perm_hi(u1.x, u0.x), a2, acc[1]);
                acc[2] = dot2bf(perm_lo(u1.y, u0.y), a2, acc[2]);
                acc[3] = dot2bf(perm_hi(u1.y, u0.y), a2, acc[3]);
                acc[4] = dot2bf(perm_lo(u1.z, u0.z), a2, acc[4]);
                acc[5] = dot2bf(perm_hi(u1.z, u0.z), a2, acc[5]);
                acc[6] = dot2bf(perm_lo(u1.w, u0.w), a2, acc[6]);
                acc[7] = dot2bf(perm_hi(u1.w, u0.w), a2, acc[7]);
            }
        }
#else
#pragma unroll
        for (int mm = 0; mm < 25; ++mm) {
            const int kk = 2 * mm + par;
            if (kk < 49) {
                const int i = kk / 7;
                const int j = kk - i * 7;
                const int row = i * 22 + j + px;
                const float a = ls[px][kk];
                const uint4 u = *(const uint4*)&win[row * 64 + (((oct + row) & 7) << 3)];
                acc[0] = fmaf(a, bf_lo(u.x), acc[0]);
                acc[1] = fmaf(a, bf_hi(u.x), acc[1]);
                acc[2] = fmaf(a, bf_lo(u.y), acc[2]);
                acc[3] = fmaf(a, bf_hi(u.y), acc[3]);
                acc[4] = fmaf(a, bf_lo(u.z), acc[4]);
                acc[5] = fmaf(a, bf_hi(u.z), acc[5]);
                acc[6] = fmaf(a, bf_lo(u.w), acc[6]);
                acc[7] = fmaf(a, bf_hi(u.w), acc[7]);
            }
        }
#endif
#pragma unroll
        for (int e = 0; e < 8; ++e) acc[e] += __shfl_xor(acc[e], 1);
        if (par == 0) {
            uint4 o;
            o.x = (unsigned)f2bf(acc[0]) | ((unsigned)f2bf(acc[1]) << 16);
            o.y = (unsigned)f2bf(acc[2]) | ((unsigned)f2bf(acc[3]) << 16);
            o.z = (unsigned)f2bf(acc[4]) | ((unsigned)f2bf(acc[5]) << 16);
            o.w = (unsigned)f2bf(acc[6]) | ((unsigned)f2bf(acc[7]) << 16);
            *(uint4*)(part_y + ((size_t)(b * TC + t) * HWPIX + gpix) * NHEAD + (oct << 3)) = o;
        }
    }
}

// ---------------------------------------------------------------------------
// K3: combine 4 t-partials + out-proj + residual (R12 version).
// ---------------------------------------------------------------------------
__global__ __launch_bounds__(256) void combine_kernel(
    const float* __restrict__ x,
    const float* __restrict__ wo_t,
    const float* __restrict__ part_ml,
    const bf16_t* __restrict__ part_y,
    float* __restrict__ out)
{
    __shared__ float y_s[16][68];

    const int tid = threadIdx.x;
    const int px  = tid >> 4;
    const int sub = tid & 15;
    const int Y0  = blockIdx.x * 16;
    const int X   = blockIdx.y;
    const int bz  = blockIdx.z;
    const int b   = bz >> 2;
    const int cg  = bz & 3;
    const int gpix = X * WW + Y0 + px;

    const float* mlb = part_ml + ((size_t)b * TC * HWPIX + gpix) * 2;
    float mt[TC], lt[TC];
#pragma unroll
    for (int t = 0; t < TC; ++t) {
        const float2 ml = *(const float2*)(mlb + (size_t)t * HWPIX * 2);
        mt[t] = ml.x; lt[t] = ml.y;
    }
    const float M = fmaxf(fmaxf(mt[0], mt[1]), fmaxf(mt[2], mt[3]));
    float st[TC], L = 0.f;
#pragma unroll
    for (int t = 0; t < TC; ++t) { st[t] = __expf(mt[t] - M); L += lt[t] * st[t]; }
    const float inv = 1.0f / L;
#pragma unroll
    for (int t = 0; t < TC; ++t) st[t] *= inv;

    float4 acc = make_float4(0.f, 0.f, 0.f, 0.f);
    const bf16_t* pyb = part_y + ((size_t)b * TC * HWPIX + gpix) * NHEAD + (sub << 2);
#pragma unroll
    for (int t = 0; t < TC; ++t) {
        const ushort4 u = *(const ushort4*)(pyb + (size_t)t * HWPIX * NHEAD);
        const float s = st[t];
        acc.x = fmaf(s, __uint_as_float(((unsigned)u.x) << 16), acc.x);
        acc.y = fmaf(s, __uint_as_float(((unsigned)u.y) << 16), acc.y);
        acc.z = fmaf(s, __uint_as_float(((unsigned)u.z) << 16), acc.z);
        acc.w = fmaf(s, __uint_as_float(((unsigned)u.w) << 16), acc.w);
    }
    *(float4*)&y_s[px][sub * 4] = acc;
    __syncthreads();

    {
        const int c0 = cg * 32 + sub * 2;
        float o0 = 0.f, o1 = 0.f;
        for (int h0 = 0; h0 < NHEAD; h0 += 4) {
            float yv[4];
            *(float4*)yv = *(const float4*)&y_s[px][h0];
#pragma unroll
            for (int e = 0; e < 4; ++e) {
                const float2 w2 = *(const float2*)(wo_t + (size_t)(h0 + e) * CCH + c0);
                o0 = fmaf(w2.x, yv[e], o0);
                o1 = fmaf(w2.y, yv[e], o1);
            }
        }
        const float xi0 = x[((size_t)(b * CCH + c0    ) * TT) * HWPIX + gpix];
        const float xi1 = x[((size_t)(b * CCH + c0 + 1) * TT) * HWPIX + gpix];
        out[(size_t)(b * CCH + c0    ) * HWPIX + gpix] = xi0 + o0;
        out[(size_t)(b * CCH + c0 + 1) * HWPIX + gpix] = xi1 + o1;
    }
}

// ---------------------------------------------------------------------------
extern "C" void kernel_launch(void* const* d_in, const int* in_sizes, int n_in,
                              void* d_out, int out_size, void* d_ws, size_t ws_size,
                              hipStream_t stream)
{
    const float* x       = (const float*)d_in[0];
    const float* w_theta = (const float*)d_in[1];
    const float* w_phi   = (const float*)d_in[2];
    const float* w_g     = (const float*)d_in[3];
    const float* w_out   = (const float*)d_in[4];
    float* out = (float*)d_out;

    bf16_t* q_b    = (bf16_t*)d_ws;                              // 294912 us
    bf16_t* phi_b  = q_b + (size_t)BATCH * HWPIX * NHEAD;        // 1548288 us
    bf16_t* g_b    = phi_b + (size_t)BATCH * TC * PLANE;         // 1548288 us
    uint4*  wt_pk  = (uint4*)(g_b + (size_t)BATCH * TC * PLANE); // 1024 u4
    uint4*  wp_pk  = wt_pk + 1024;
    uint4*  wg_pk  = wp_pk + 1024;
    float*  wo_t   = (float*)(wg_pk + 1024);                     // 8192 f
    float*  part_ml = wo_t + 8192;                               // 36864 f
    bf16_t* part_y  = (bf16_t*)(part_ml + 36864);                // 1179648 us

    wtrans_kernel<<<20, 256, 0, stream>>>(w_theta, w_phi, w_g, w_out,
                                          wt_pk, wp_pk, wg_pk, wo_t);

    dim3 g1(HWPIX / 16, BATCH * TT);            // (144, 10)
    proj_kernel<<<g1, 256, 0, stream>>>(x, wt_pk, wp_pk, wg_pk, q_b, phi_b, g_b);

    attn_kernel<<<BATCH * TC * HH * (WW / 16), 256, 0, stream>>>(
        q_b, phi_b, g_b, part_ml, part_y);      // 1152 blocks

    dim3 g3(WW / 16, HH, BATCH * 4);            // (3, 48, 8)
    combine_kernel<<<g3, 256, 0, stream>>>(x, wo_t, part_ml, part_y, out);
}

// Round 15
// 108.917 us; speedup vs baseline: 1.1237x; 1.1237x over previous
//
#include <hip/hip_runtime.h>
#include <hip/hip_bf16.h>
#include <math.h>

// B=2, C=128, T=5 (Tc=4 ctx), H=W=48, heads=64, PATCH=7 (pad 3), K=196.
#define BATCH 2
#define CCH 128
#define TT 5
#define TC 4
#define HH 48
#define WW 48
#define HWPIX 2304
#define NHEAD 64
#define PAD 3
#define XSTRIDE (TT*HWPIX)      // per-channel stride in x
#define ROWP 54                 // 48 + 2*3 padded rows
#define COLP 56                 // 48 + 2*3 padded cols (+2 align slack)
#define PLANE (ROWP*COLP*NHEAD) // elements per (b,t) plane

typedef unsigned short bf16_t;

static __device__ __forceinline__ bf16_t f2bf(float f) {
    unsigned u = __float_as_uint(f);
    u += 0x7FFFu + ((u >> 16) & 1u);          // round-to-nearest-even
    return (bf16_t)(u >> 16);
}
static __device__ __forceinline__ float bf_lo(unsigned u) {
    return __uint_as_float(u << 16);
}
static __device__ __forceinline__ float bf_hi(unsigned u) {
    return __uint_as_float(u & 0xFFFF0000u);
}

// v_dot2_f32_bf16 path (hedged: falls back to unpack+fma if unavailable)
#if defined(__has_builtin)
#if __has_builtin(__builtin_amdgcn_fdot2_f32_bf16) && __has_builtin(__builtin_amdgcn_perm)
#define HAVE_DOT2 1
#endif
#endif

#ifdef HAVE_DOT2
typedef __bf16 bf16x2_t __attribute__((ext_vector_type(2)));
static __device__ __forceinline__ float dot2bf(unsigned g2, unsigned a2, float c) {
    return __builtin_amdgcn_fdot2_f32_bf16(
        __builtin_bit_cast(bf16x2_t, g2), __builtin_bit_cast(bf16x2_t, a2), c, false);
}
static __device__ __forceinline__ unsigned perm_lo(unsigned a, unsigned b) {
    return __builtin_amdgcn_perm(a, b, 0x05040100u);
}
static __device__ __forceinline__ unsigned perm_hi(unsigned a, unsigned b) {
    return __builtin_amdgcn_perm(a, b, 0x07060302u);
}
#else
static __device__ __forceinline__ float dot2bf(unsigned g2, unsigned a2, float c) {
    return c + bf_lo(g2) * bf_lo(a2) + bf_hi(g2) * bf_hi(a2);
}
#endif

// ---------------------------------------------------------------------------
// K0: weight reshapes, 20 blocks.
// wt/wp/wg_pk: [16 chunk][64 h] uint4 = 4 bf16-pairs (8 consecutive c).
// wo_t: [64h][128c] fp32 transpose of w_out.
// ---------------------------------------------------------------------------
__global__ __launch_bounds__(256) void wtrans_kernel(
    const float* __restrict__ w_theta,
    const float* __restrict__ w_phi,
    const float* __restrict__ w_g,
    const float* __restrict__ w_out,
    uint4* __restrict__ wt_pk,
    uint4* __restrict__ wp_pk,
    uint4* __restrict__ wg_pk,
    float* __restrict__ wo_t)
{
    const int blk = blockIdx.x;          // 0..19
    const int tid = threadIdx.x;
    if (blk < 12) {
        const float* srcs[3] = {w_theta, w_phi, w_g};
        uint4*       dsts[3] = {wt_pk, wp_pk, wg_pk};
        const int a   = blk >> 2;
        const int idx = ((blk & 3) << 8) | tid;   // 0..1023
        const int h   = idx >> 4;                 // 0..63
        const int ck  = idx & 15;                 // chunk 0..15
        const float* s = srcs[a] + h * CCH + ck * 8;
        uint4 o;
        o.x = (unsigned)f2bf(s[0]) | ((unsigned)f2bf(s[1]) << 16);
        o.y = (unsigned)f2bf(s[2]) | ((unsigned)f2bf(s[3]) << 16);
        o.z = (unsigned)f2bf(s[4]) | ((unsigned)f2bf(s[5]) << 16);
        o.w = (unsigned)f2bf(s[6]) | ((unsigned)f2bf(s[7]) << 16);
        dsts[a][(ck << 6) | h] = o;
    } else {
        const int idx = ((blk - 12) << 8) | tid;  // 0..2047
        const int c   = idx >> 4;
        const int hq  = idx & 15;
        const float4 v = *(const float4*)(w_out + c * NHEAD + hq * 4);
        wo_t[(hq * 4 + 0) * CCH + c] = v.x;
        wo_t[(hq * 4 + 1) * CCH + c] = v.y;
        wo_t[(hq * 4 + 2) * CCH + c] = v.z;
        wo_t[(hq * 4 + 3) * CCH + c] = v.w;
    }
}

// ---------------------------------------------------------------------------
// K1: projections, fully LDS-resident inner loop, bf16 dot2 math.
// Block = 16 px of one (b,t). Stage: weights (16/32 KB) + x as bf16 pairs
// (4.25 KB). Compute: lane = head, wave = px-quad; per chunk: 1-2 lane-b128
// weight reads + 4 broadcast-b128 x reads + 16/32 dot2. No global access in
// the K-loop. q bf16; phi_b/g_b bf16 padded planes (replicate borders).
// ---------------------------------------------------------------------------
__global__ __launch_bounds__(256) void proj_kernel(
    const float* __restrict__ x,
    const uint4* __restrict__ wt_pk,
    const uint4* __restrict__ wp_pk,
    const uint4* __restrict__ wg_pk,
    bf16_t* __restrict__ q_b,
    bf16_t* __restrict__ phi_b,
    bf16_t* __restrict__ g_b)
{
    __shared__ unsigned xs[16 * 68];    // 4.25 KB (bf16 c-pairs, pitch 68)
    __shared__ uint4 wlA[1024];         // 16 KB
    __shared__ uint4 wlB[1024];         // 16 KB

    const int bt   = blockIdx.y;        // 0..9
    const int b    = bt / TT;
    const int t    = bt % TT;
    const int tid  = threadIdx.x;
    const int lane = tid & 63;
    const int wv   = tid >> 6;
    const int p0   = blockIdx.x * 16;

    // ---- stage weights into LDS (coalesced uint4) ----
    {
        const uint4* srcA = (t == 0) ? wt_pk : wp_pk;
#pragma unroll
        for (int i = 0; i < 4; ++i) wlA[i * 256 + tid] = srcA[i * 256 + tid];
        if (t != 0) {
#pragma unroll
            for (int i = 0; i < 4; ++i) wlB[i * 256 + tid] = wg_pk[i * 256 + tid];
        }
    }

    // ---- stage x tile as bf16 pairs (lanes over px: coalesced) ----
    {
        const float* xsrc = x + ((size_t)(b * CCH) * TT + t) * HWPIX + p0;
#pragma unroll
        for (int i = 0; i < 4; ++i) {
            const int idx = i * 256 + tid;  // 0..1023
            const int cp  = idx >> 4;       // c-pair 0..63
            const int px  = idx & 15;
            const float a0 = xsrc[(size_t)(2 * cp)     * XSTRIDE + px];
            const float a1 = xsrc[(size_t)(2 * cp + 1) * XSTRIDE + px];
            xs[px * 68 + cp] = (unsigned)f2bf(a0) | ((unsigned)f2bf(a1) << 16);
        }
    }
    __syncthreads();

    const int pxb = wv * 4;

    if (t == 0) {
        float acc[4] = {0.f, 0.f, 0.f, 0.f};
#pragma unroll 4
        for (int ck = 0; ck < 16; ++ck) {
            const uint4 wa = wlA[(ck << 6) | lane];
#pragma unroll
            for (int p = 0; p < 4; ++p) {
                const uint4 xv = *(const uint4*)&xs[(pxb + p) * 68 + (ck << 2)];
                acc[p] = dot2bf(wa.x, xv.x, acc[p]);
                acc[p] = dot2bf(wa.y, xv.y, acc[p]);
                acc[p] = dot2bf(wa.z, xv.z, acc[p]);
                acc[p] = dot2bf(wa.w, xv.w, acc[p]);
            }
        }
#pragma unroll
        for (int p = 0; p < 4; ++p)
            q_b[((size_t)b * HWPIX + p0 + pxb + p) * NHEAD + lane] = f2bf(acc[p]);
    } else {
        float accp[4] = {0.f, 0.f, 0.f, 0.f};
        float accg[4] = {0.f, 0.f, 0.f, 0.f};
#pragma unroll 4
        for (int ck = 0; ck < 16; ++ck) {
            const uint4 wa = wlA[(ck << 6) | lane];
            const uint4 wb = wlB[(ck << 6) | lane];
#pragma unroll
            for (int p = 0; p < 4; ++p) {
                const uint4 xv = *(const uint4*)&xs[(pxb + p) * 68 + (ck << 2)];
                accp[p] = dot2bf(wa.x, xv.x, accp[p]);
                accp[p] = dot2bf(wa.y, xv.y, accp[p]);
                accp[p] = dot2bf(wa.z, xv.z, accp[p]);
                accp[p] = dot2bf(wa.w, xv.w, accp[p]);
                accg[p] = dot2bf(wb.x, xv.x, accg[p]);
                accg[p] = dot2bf(wb.y, xv.y, accg[p]);
                accg[p] = dot2bf(wb.z, xv.z, accg[p]);
                accg[p] = dot2bf(wb.w, xv.w, accg[p]);
            }
        }
        const size_t base = (size_t)(b * TC + (t - 1)) * PLANE;
#pragma unroll
        for (int p = 0; p < 4; ++p) {
            const int pix = p0 + pxb + p;
            const int X = pix / WW;
            const int Y = pix % WW;
            const int rs = (X == 0) ? 0 : (X + PAD);
            const int rn = (X == 0 || X == HH - 1) ? (PAD + 1) : 1;
            const int cs = (Y == 0) ? 0 : (Y + PAD);
            const int cn = (Y == 0 || Y == WW - 1) ? (PAD + 1) : 1;
            const bf16_t vp = f2bf(accp[p]);
            const bf16_t vg = f2bf(accg[p]);
            for (int r = 0; r < rn; ++r)
                for (int c = 0; c < cn; ++c) {
                    const size_t pos = base + ((size_t)(rs + r) * COLP + (cs + c)) * NHEAD + lane;
                    phi_b[pos] = vp;
                    g_b[pos]   = vg;
                }
        }
    }
}

// ---------------------------------------------------------------------------
// K2: per-t attention partial (R12 optimum). Raw bf16 windows in LDS,
// bf16 q, dot2 both phases. Single window buffer, serialized staging —
// inter-block overlap at ~6 blocks/CU hides the fetches (R13/R14 falsified
// intra-block alternatives).
// ---------------------------------------------------------------------------
__global__ __launch_bounds__(256) void attn_kernel(
    const bf16_t* __restrict__ q_b,
    const bf16_t* __restrict__ phi_b,
    const bf16_t* __restrict__ g_b,
    float* __restrict__ part_ml,
    bf16_t* __restrict__ part_y)
{
    __shared__ bf16_t win[154 * NHEAD];     // 19.7 KB raw bf16, swizzled
    __shared__ float ls[16][52];            // 49 exp-weights per px
    __shared__ unsigned ls2[16][26];        // packed (a_2m, a_2m+1) bf16 pairs
    __shared__ unsigned prow[26];           // (row0 | row1<<16) per pair

    const int tid = threadIdx.x;
    const int px  = tid >> 4;
    const int sub = tid & 15;
    const int bi  = blockIdx.x;
    const int btc = bi & 7;                 // b*4 + t
    const int b   = btc >> 2;
    const int t   = btc & 3;
    const int rest = bi >> 3;               // 0..143
    const int Y0  = (rest % 3) * 16;
    const int X   = rest / 3;               // 0..47
    const int gpix = X * WW + Y0 + px;

    uint4 qu[8];
    {
        const uint4* qs = (const uint4*)(q_b + ((size_t)b * HWPIX + gpix) * NHEAD);
#pragma unroll
        for (int ch = 0; ch < 8; ++ch) qu[ch] = qs[ch];
    }

    if (tid < 25) {
        const int k0 = 2 * tid;
        const int k1 = (k0 + 1 < 49) ? k0 + 1 : 48;
        const unsigned r0 = (k0 / 7) * 22 + (k0 % 7);
        const unsigned r1 = (k1 / 7) * 22 + (k1 % 7);
        prow[tid] = r0 | (r1 << 16);
    }

    // ---- stage phi window (raw bf16, slot swizzle (ch+row)&7) ----
    {
        const bf16_t* src = phi_b + (size_t)(b * TC + t) * PLANE;
        for (int idx = tid; idx < 1232; idx += 256) {
            const int row = idx >> 3;
            const int ch  = idx & 7;
            const int i   = row / 22;
            const int c   = row - i * 22;
            const uint4 u = *(const uint4*)(src + ((size_t)((X + i) * COLP) + Y0 + c) * NHEAD + ch * 8);
            *(uint4*)&win[row * 64 + (((ch + row) & 7) << 3)] = u;
        }
    }
    __syncthreads();

    // ---- 49-key logits ----
    float v[4];
#pragma unroll
    for (int r = 0; r < 4; ++r) {
        const int k = sub + 16 * r;
        float d = -INFINITY;
        if (k < 49) {
            const int i = k / 7;
            const int j = k - i * 7;
            const int row = i * 22 + j + px;
            const bf16_t* base = &win[row * 64];
            float s = 0.f;
#pragma unroll
            for (int ch = 0; ch < 8; ++ch) {
                const uint4 u = *(const uint4*)&base[((ch + row) & 7) << 3];
                s = dot2bf(u.x, qu[ch].x, s);
                s = dot2bf(u.y, qu[ch].y, s);
                s = dot2bf(u.z, qu[ch].z, s);
                s = dot2bf(u.w, qu[ch].w, s);
            }
            d = s * 8.0f;    // * sqrt(64)
        }
        v[r] = d;
    }
    float m = fmaxf(fmaxf(v[0], v[1]), fmaxf(v[2], v[3]));
#pragma unroll
    for (int d = 1; d < 16; d <<= 1) m = fmaxf(m, __shfl_xor(m, d));
    float lsum = 0.f;
#pragma unroll
    for (int r = 0; r < 4; ++r) {
        const int k = sub + 16 * r;
        if (k < 49) {
            const float e = __expf(v[r] - m);
            ls[px][k] = e;
            lsum += e;
        }
    }
#pragma unroll
    for (int d = 1; d < 16; d <<= 1) lsum += __shfl_xor(lsum, d);
    if (sub == 0) {
        *(float2*)&part_ml[((size_t)(b * TC + t) * HWPIX + gpix) * 2] = make_float2(m, lsum);
    }

#pragma unroll
    for (int mq = 0; mq < 2; ++mq) {
        const int mm = sub + 16 * mq;
        if (mm < 25) {
            const float a0 = ls[px][2 * mm];
            const float a1 = (2 * mm + 1 < 49) ? ls[px][2 * mm + 1] : 0.f;
            ls2[px][mm] = (unsigned)f2bf(a0) | ((unsigned)f2bf(a1) << 16);
        }
    }
    __syncthreads();

    // ---- stage g window ----
    {
        const bf16_t* src = g_b + (size_t)(b * TC + t) * PLANE;
        for (int idx = tid; idx < 1232; idx += 256) {
            const int row = idx >> 3;
            const int ch  = idx & 7;
            const int i   = row / 22;
            const int c   = row - i * 22;
            const uint4 u = *(const uint4*)(src + ((size_t)((X + i) * COLP) + Y0 + c) * NHEAD + ch * 8);
            *(uint4*)&win[row * 64 + (((ch + row) & 7) << 3)] = u;
        }
    }
    __syncthreads();

    // ---- unnormalized y partial: thread = (px, oct, par) over key-pairs ----
    {
        const int oct = sub >> 1;
        const int par = sub & 1;
        float acc[8];
#pragma unroll
        for (int e = 0; e < 8; ++e) acc[e] = 0.f;
#ifdef HAVE_DOT2
#pragma unroll
        for (int mm = 0; mm < 13; ++mm) {
            const int pm = 2 * mm + par;
            if (pm < 25) {
                const unsigned pr = prow[pm];
                const int row0 = (int)(pr & 0xFFFFu) + px;
                const int row1 = (int)(pr >> 16) + px;
                const unsigned a2 = ls2[px][pm];
                const uint4 u0 = *(const uint4*)&win[row0 * 64 + (((oct + row0) & 7) << 3)];
                const uint4 u1 = *(const uint4*)&win[row1 * 64 + (((oct + row1) & 7) << 3)];
                acc[0] = dot2bf(perm_lo(u1.x, u0.x), a2, acc[0]);
                acc[1] = dot2bf(perm_hi(u1.x, u0.x), a2, acc[1]);
                acc[2] = dot2bf(perm_lo(u1.y, u0.y), a2, acc[2]);
                acc[3] = dot2bf(perm_hi(u1.y, u0.y), a2, acc[3]);
                acc[4] = dot2bf(perm_lo(u1.z, u0.z), a2, acc[4]);
                acc[5] = dot2bf(perm_hi(u1.z, u0.z), a2, acc[5]);
                acc[6] = dot2bf(perm_lo(u1.w, u0.w), a2, acc[6]);
                acc[7] = dot2bf(perm_hi(u1.w, u0.w), a2, acc[7]);
            }
        }
#else
#pragma unroll
        for (int mm = 0; mm < 25; ++mm) {
            const int kk = 2 * mm + par;
            if (kk < 49) {
                const int i = kk / 7;
                const int j = kk - i * 7;
                const int row = i * 22 + j + px;
                const float a = ls[px][kk];
                const uint4 u = *(const uint4*)&win[row * 64 + (((oct + row) & 7) << 3)];
                acc[0] = fmaf(a, bf_lo(u.x), acc[0]);
                acc[1] = fmaf(a, bf_hi(u.x), acc[1]);
                acc[2] = fmaf(a, bf_lo(u.y), acc[2]);
                acc[3] = fmaf(a, bf_hi(u.y), acc[3]);
                acc[4] = fmaf(a, bf_lo(u.z), acc[4]);
                acc[5] = fmaf(a, bf_hi(u.z), acc[5]);
                acc[6] = fmaf(a, bf_lo(u.w), acc[6]);
                acc[7] = fmaf(a, bf_hi(u.w), acc[7]);
            }
        }
#endif
#pragma unroll
        for (int e = 0; e < 8; ++e) acc[e] += __shfl_xor(acc[e], 1);
        if (par == 0) {
            uint4 o;
            o.x = (unsigned)f2bf(acc[0]) | ((unsigned)f2bf(acc[1]) << 16);
            o.y = (unsigned)f2bf(acc[2]) | ((unsigned)f2bf(acc[3]) << 16);
            o.z = (unsigned)f2bf(acc[4]) | ((unsigned)f2bf(acc[5]) << 16);
            o.w = (unsigned)f2bf(acc[6]) | ((unsigned)f2bf(acc[7]) << 16);
            *(uint4*)(part_y + ((size_t)(b * TC + t) * HWPIX + gpix) * NHEAD + (oct << 3)) = o;
        }
    }
}

// ---------------------------------------------------------------------------
// K3: combine 4 t-partials + out-proj + residual. Grid (3,48,8): z = b*4+cg.
// ---------------------------------------------------------------------------
__global__ __launch_bounds__(256) void combine_kernel(
    const float* __restrict__ x,
    const float* __restrict__ wo_t,
    const float* __restrict__ part_ml,
    const bf16_t* __restrict__ part_y,
    float* __restrict__ out)
{
    __shared__ float y_s[16][68];

    const int tid = threadIdx.x;
    const int px  = tid >> 4;
    const int sub = tid & 15;
    const int Y0  = blockIdx.x * 16;
    const int X   = blockIdx.y;
    const int bz  = blockIdx.z;
    const int b   = bz >> 2;
    const int cg  = bz & 3;
    const int gpix = X * WW + Y0 + px;

    const float* mlb = part_ml + ((size_t)b * TC * HWPIX + gpix) * 2;
    float mt[TC], lt[TC];
#pragma unroll
    for (int t = 0; t < TC; ++t) {
        const float2 ml = *(const float2*)(mlb + (size_t)t * HWPIX * 2);
        mt[t] = ml.x; lt[t] = ml.y;
    }
    const float M = fmaxf(fmaxf(mt[0], mt[1]), fmaxf(mt[2], mt[3]));
    float st[TC], L = 0.f;
#pragma unroll
    for (int t = 0; t < TC; ++t) { st[t] = __expf(mt[t] - M); L += lt[t] * st[t]; }
    const float inv = 1.0f / L;
#pragma unroll
    for (int t = 0; t < TC; ++t) st[t] *= inv;

    float4 acc = make_float4(0.f, 0.f, 0.f, 0.f);
    const bf16_t* pyb = part_y + ((size_t)b * TC * HWPIX + gpix) * NHEAD + (sub << 2);
#pragma unroll
    for (int t = 0; t < TC; ++t) {
        const ushort4 u = *(const ushort4*)(pyb + (size_t)t * HWPIX * NHEAD);
        const float s = st[t];
        acc.x = fmaf(s, __uint_as_float(((unsigned)u.x) << 16), acc.x);
        acc.y = fmaf(s, __uint_as_float(((unsigned)u.y) << 16), acc.y);
        acc.z = fmaf(s, __uint_as_float(((unsigned)u.z) << 16), acc.z);
        acc.w = fmaf(s, __uint_as_float(((unsigned)u.w) << 16), acc.w);
    }
    *(float4*)&y_s[px][sub * 4] = acc;
    __syncthreads();

    {
        const int c0 = cg * 32 + sub * 2;
        float o0 = 0.f, o1 = 0.f;
        for (int h0 = 0; h0 < NHEAD; h0 += 4) {
            float yv[4];
            *(float4*)yv = *(const float4*)&y_s[px][h0];
#pragma unroll
            for (int e = 0; e < 4; ++e) {
                const float2 w2 = *(const float2*)(wo_t + (size_t)(h0 + e) * CCH + c0);
                o0 = fmaf(w2.x, yv[e], o0);
                o1 = fmaf(w2.y, yv[e], o1);
            }
        }
        const float xi0 = x[((size_t)(b * CCH + c0    ) * TT) * HWPIX + gpix];
        const float xi1 = x[((size_t)(b * CCH + c0 + 1) * TT) * HWPIX + gpix];
        out[(size_t)(b * CCH + c0    ) * HWPIX + gpix] = xi0 + o0;
        out[(size_t)(b * CCH + c0 + 1) * HWPIX + gpix] = xi1 + o1;
    }
}

// ---------------------------------------------------------------------------
extern "C" void kernel_launch(void* const* d_in, const int* in_sizes, int n_in,
                              void* d_out, int out_size, void* d_ws, size_t ws_size,
                              hipStream_t stream)
{
    const float* x       = (const float*)d_in[0];
    const float* w_theta = (const float*)d_in[1];
    const float* w_phi   = (const float*)d_in[2];
    const float* w_g     = (const float*)d_in[3];
    const float* w_out   = (const float*)d_in[4];
    float* out = (float*)d_out;

    bf16_t* q_b    = (bf16_t*)d_ws;                              // 294912 us
    bf16_t* phi_b  = q_b + (size_t)BATCH * HWPIX * NHEAD;        // 1548288 us
    bf16_t* g_b    = phi_b + (size_t)BATCH * TC * PLANE;         // 1548288 us
    uint4*  wt_pk  = (uint4*)(g_b + (size_t)BATCH * TC * PLANE); // 1024 u4
    uint4*  wp_pk  = wt_pk + 1024;
    uint4*  wg_pk  = wp_pk + 1024;
    float*  wo_t   = (float*)(wg_pk + 1024);                     // 8192 f
    float*  part_ml = wo_t + 8192;                               // 36864 f
    bf16_t* part_y  = (bf16_t*)(part_ml + 36864);                // 1179648 us

    wtrans_kernel<<<20, 256, 0, stream>>>(w_theta, w_phi, w_g, w_out,
                                          wt_pk, wp_pk, wg_pk, wo_t);

    dim3 g1(HWPIX / 16, BATCH * TT);            // (144, 10)
    proj_kernel<<<g1, 256, 0, stream>>>(x, wt_pk, wp_pk, wg_pk, q_b, phi_b, g_b);

    attn_kernel<<<BATCH * TC * HH * (WW / 16), 256, 0, stream>>>(
        q_b, phi_b, g_b, part_ml, part_y);      // 1152 blocks

    dim3 g3(WW / 16, HH, BATCH * 4);            // (3, 48, 8)
    combine_kernel<<<g3, 256, 0, stream>>>(x, wo_t, part_ml, part_y, out);
}